// Round 5
// baseline (743.523 us; speedup 1.0000x reference)
//
#include <hip/hip_runtime.h>
#include <math.h>

#define EPT 16
#define CHUNK (256 * EPT)  // 4096 edges per scatter block
#define CAP 12288          // fixed bucket segment capacity (mean 8192, +45 sigma)

// ================= bucket CSR build (fixed segments, no global scan) =================
// Bucket b = nodes [256b, 256(b+1)); segment [b*CAP, b*CAP + bfill[b]).
// Requires n < 65536 (pack (local<<16)|src).

// scatter packed edges into fixed bucket segments; one block = 4096 edges,
// block reserves per-bucket ranges with ONE global atomic per touched bucket
__global__ void bucket_scatter_k(const int* __restrict__ src, const int* __restrict__ dst,
                                 int* __restrict__ bfill, unsigned int* __restrict__ bpk,
                                 int E) {
    __shared__ int hist[256], gofs[256], lfill[256];
    int t = threadIdx.x;
    int base = blockIdx.x * CHUNK;
    hist[t] = 0;
    lfill[t] = 0;
    __syncthreads();
    int ds[EPT], ss[EPT];
#pragma unroll
    for (int i = 0; i < EPT; ++i) {
        int e = base + i * 256 + t;
        if (e < E) {
            ds[i] = dst[e];
            ss[i] = src[e];
            atomicAdd(&hist[ds[i] >> 8], 1);
        } else {
            ds[i] = -1;
        }
    }
    __syncthreads();
    if (hist[t]) gofs[t] = atomicAdd(&bfill[t], hist[t]);
    __syncthreads();
#pragma unroll
    for (int i = 0; i < EPT; ++i) {
        if (ds[i] >= 0) {
            int b = ds[i] >> 8;
            int p = atomicAdd(&lfill[b], 1);
            int idx = gofs[b] + p;
            if (idx < CAP)  // overflow guard (should never trigger at 45 sigma)
                bpk[b * CAP + idx] = ((unsigned)(ds[i] & 255) << 16) | (unsigned)ss[i];
        }
    }
}

// one block per bucket: local histogram -> deg/dinv/rbeg/rend, LDS counting-sort,
// coalesced csr (ushort) write into the fixed segment
__global__ void bucket_build_k(const unsigned int* __restrict__ bpk,
                               const int* __restrict__ bfill,
                               unsigned short* __restrict__ csr,
                               int* __restrict__ rbeg, int* __restrict__ rend,
                               float* __restrict__ dinv, int n) {
    __shared__ int hist[256], loff[256], lfill[256], tmp[256];
    __shared__ unsigned short scsr[CAP];
    int b = blockIdx.x, t = threadIdx.x;
    int base = b * CAP;
    int bsize = min(bfill[b], CAP);
    hist[t] = 0;
    lfill[t] = 0;
    __syncthreads();
    for (int idx = t; idx < bsize; idx += 256)
        atomicAdd(&hist[bpk[base + idx] >> 16], 1);
    __syncthreads();
    int deg = hist[t];
    tmp[t] = deg;
    __syncthreads();
    for (int off = 1; off < 256; off <<= 1) {
        int a = (t >= off) ? tmp[t - off] : 0;
        __syncthreads();
        tmp[t] += a;
        __syncthreads();
    }
    loff[t] = tmp[t] - deg;  // exclusive
    int node = (b << 8) + t;
    if (node < n) {
        rbeg[node] = base + loff[t];
        rend[node] = base + loff[t] + deg;
        dinv[node] = rsqrtf((float)(deg + 1));  // +1 self-loop
    }
    __syncthreads();
    for (int idx = t; idx < bsize; idx += 256) {
        unsigned u = bpk[base + idx];
        int ln = (int)(u >> 16);
        int sp = atomicAdd(&lfill[ln], 1);
        scsr[loff[ln] + sp] = (unsigned short)(u & 0xFFFFu);
    }
    __syncthreads();
    for (int idx = t; idx < bsize; idx += 256)
        csr[base + idx] = scsr[idx];
}

// ================= GEMM1 (fp32 vector ALU), dinv-scaled epilogue =================
// hs[n,128] = (x[n,256] @ W[256,128]) * dinv[row]; 16 rows/block, 128 threads

__global__ void gemm1_k(const float* __restrict__ x, const float* __restrict__ W,
                        const float* __restrict__ dinv, float* __restrict__ hs, int n) {
    int r0 = blockIdx.x * 16;
    int t = threadIdx.x;  // 0..127 -> output column
    __shared__ float xs[16][256];
    float4* xsv = (float4*)&xs[0][0];
    const float4* xg = (const float4*)(x + (long long)r0 * 256);
    if (r0 + 16 <= n) {
        for (int v = t; v < 16 * 64; v += 128) xsv[v] = xg[v];
    } else {
        for (int v = t; v < 16 * 64; v += 128) {
            int r = v >> 6;
            xsv[v] = (r0 + r < n) ? xg[v] : make_float4(0.f, 0.f, 0.f, 0.f);
        }
    }
    __syncthreads();
    float acc[16];
#pragma unroll
    for (int r = 0; r < 16; ++r) acc[r] = 0.0f;
    for (int k = 0; k < 256; k += 4) {
        float w0 = W[(k + 0) * 128 + t];
        float w1 = W[(k + 1) * 128 + t];
        float w2 = W[(k + 2) * 128 + t];
        float w3 = W[(k + 3) * 128 + t];
#pragma unroll
        for (int r = 0; r < 16; ++r) {
            float4 xv = *(const float4*)&xs[r][k];  // ds_read_b128
            acc[r] += xv.x * w0 + xv.y * w1 + xv.z * w2 + xv.w * w3;
        }
    }
#pragma unroll
    for (int r = 0; r < 16; ++r) {
        int row = r0 + r;
        if (row < n) hs[(long long)row * 128 + t] = acc[r] * dinv[row];
    }
}

// ================= fused layer-1 gather + GEMM2 =================
// Phase A: h1[i] = relu(dinv[i]*(hs[i] + sum_nb hs[j]) + b1) -> LDS (never to HBM)
// Phase B: hs2[i,64] = (h1[i] @ W2) * dinv[i]
// 8 nodes/block, 256 threads

__global__ void layer1_k(const float* __restrict__ hs, const int* __restrict__ rbeg,
                         const int* __restrict__ rend, const unsigned short* __restrict__ csr,
                         const float* __restrict__ dinv, const float* __restrict__ b1,
                         const float* __restrict__ W2, float* __restrict__ hs2, int n) {
    __shared__ float h1s[8][128];
    __shared__ float dv[8];
    int t = threadIdx.x;
    int g = t >> 5, lane = t & 31;
    int i = blockIdx.x * 8 + g;
    bool valid = (i < n);
    float4 acc = make_float4(0.f, 0.f, 0.f, 0.f);
    int beg = 0, end = 0;
    float di = 0.0f;
    if (valid) {
        acc = ((const float4*)(hs + (long long)i * 128))[lane];  // self term
        beg = rbeg[i];
        end = rend[i];
        di = dinv[i];
        if (lane == 0) dv[g] = di;
    }
    int j = beg;
    for (; j + 4 <= end; j += 4) {
        int s0 = csr[j], s1 = csr[j + 1], s2 = csr[j + 2], s3 = csr[j + 3];
        float4 v0 = ((const float4*)(hs + (long long)s0 * 128))[lane];
        float4 v1 = ((const float4*)(hs + (long long)s1 * 128))[lane];
        float4 v2 = ((const float4*)(hs + (long long)s2 * 128))[lane];
        float4 v3 = ((const float4*)(hs + (long long)s3 * 128))[lane];
        acc.x += v0.x + v1.x + v2.x + v3.x;
        acc.y += v0.y + v1.y + v2.y + v3.y;
        acc.z += v0.z + v1.z + v2.z + v3.z;
        acc.w += v0.w + v1.w + v2.w + v3.w;
    }
    for (; j < end; ++j) {
        int s0 = csr[j];
        float4 v0 = ((const float4*)(hs + (long long)s0 * 128))[lane];
        acc.x += v0.x; acc.y += v0.y; acc.z += v0.z; acc.w += v0.w;
    }
    float4 bb = ((const float4*)b1)[lane];
    float4 o;
    o.x = valid ? fmaxf(di * acc.x + bb.x, 0.0f) : 0.0f;
    o.y = valid ? fmaxf(di * acc.y + bb.y, 0.0f) : 0.0f;
    o.z = valid ? fmaxf(di * acc.z + bb.z, 0.0f) : 0.0f;
    o.w = valid ? fmaxf(di * acc.w + bb.w, 0.0f) : 0.0f;
    *(float4*)&h1s[g][lane * 4] = o;
    __syncthreads();

    // Phase B: 4 waves; wave w handles nodes {w, w+4}, cols 0..63
    int col = t & 63;
    int n0 = t >> 6;  // 0..3
    float a0 = 0.0f, a1 = 0.0f;
    for (int k4 = 0; k4 < 32; ++k4) {
        float4 h0v = *(const float4*)&h1s[n0][k4 * 4];      // LDS broadcast
        float4 h4v = *(const float4*)&h1s[n0 + 4][k4 * 4];
        float w0 = W2[(k4 * 4 + 0) * 64 + col];
        float w1 = W2[(k4 * 4 + 1) * 64 + col];
        float w2 = W2[(k4 * 4 + 2) * 64 + col];
        float w3 = W2[(k4 * 4 + 3) * 64 + col];
        a0 += h0v.x * w0 + h0v.y * w1 + h0v.z * w2 + h0v.w * w3;
        a1 += h4v.x * w0 + h4v.y * w1 + h4v.z * w2 + h4v.w * w3;
    }
    int i0 = blockIdx.x * 8 + n0;
    int i1 = i0 + 4;
    if (i0 < n) hs2[(long long)i0 * 64 + col] = a0 * dv[n0];
    if (i1 < n) hs2[(long long)i1 * 64 + col] = a1 * dv[n0 + 4];
}

// ================= layer-2 gather + sigmoid/threshold epilogue =================
// out[0:t)=pred, out[t:2t)=prob; C=64, 16 lanes/node, 16 nodes/block

__global__ void gather2_k(const float* __restrict__ hs2, const int* __restrict__ rbeg,
                          const int* __restrict__ rend, const unsigned short* __restrict__ csr,
                          const float* __restrict__ dinv, const float* __restrict__ b2,
                          float* __restrict__ out, int n) {
    int g = threadIdx.x >> 4;
    int lane = threadIdx.x & 15;
    int i = blockIdx.x * 16 + g;
    if (i >= n) return;
    float4 acc = ((const float4*)(hs2 + (long long)i * 64))[lane];  // self term
    int beg = rbeg[i], end = rend[i];
    int j = beg;
    for (; j + 4 <= end; j += 4) {
        int s0 = csr[j], s1 = csr[j + 1], s2 = csr[j + 2], s3 = csr[j + 3];
        float4 v0 = ((const float4*)(hs2 + (long long)s0 * 64))[lane];
        float4 v1 = ((const float4*)(hs2 + (long long)s1 * 64))[lane];
        float4 v2 = ((const float4*)(hs2 + (long long)s2 * 64))[lane];
        float4 v3 = ((const float4*)(hs2 + (long long)s3 * 64))[lane];
        acc.x += v0.x + v1.x + v2.x + v3.x;
        acc.y += v0.y + v1.y + v2.y + v3.y;
        acc.z += v0.z + v1.z + v2.z + v3.z;
        acc.w += v0.w + v1.w + v2.w + v3.w;
    }
    for (; j < end; ++j) {
        int s0 = csr[j];
        float4 v0 = ((const float4*)(hs2 + (long long)s0 * 64))[lane];
        acc.x += v0.x; acc.y += v0.y; acc.z += v0.z; acc.w += v0.w;
    }
    float di = dinv[i];
    float4 bb = ((const float4*)b2)[lane];
    float lx = di * acc.x + bb.x;
    float ly = di * acc.y + bb.y;
    float lz = di * acc.z + bb.z;
    float lw = di * acc.w + bb.w;
    float4 p;
    p.x = 1.0f / (1.0f + expf(-lx));
    p.y = 1.0f / (1.0f + expf(-ly));
    p.z = 1.0f / (1.0f + expf(-lz));
    p.w = 1.0f / (1.0f + expf(-lw));
    long long total = (long long)n * 64;
    long long o0 = (long long)i * 64 + lane * 4;
    float4 pr;
    pr.x = (p.x > 0.5f) ? 1.0f : 0.0f;
    pr.y = (p.y > 0.5f) ? 1.0f : 0.0f;
    pr.z = (p.z > 0.5f) ? 1.0f : 0.0f;
    pr.w = (p.w > 0.5f) ? 1.0f : 0.0f;
    *(float4*)(out + o0) = pr;
    *(float4*)(out + total + o0) = p;
}

// ================= launch =================

extern "C" void kernel_launch(void* const* d_in, const int* in_sizes, int n_in,
                              void* d_out, int out_size, void* d_ws, size_t ws_size,
                              hipStream_t stream) {
    const float* x  = (const float*)d_in[0];
    const int*   ei = (const int*)d_in[1];
    const float* W1 = (const float*)d_in[2];
    const float* b1 = (const float*)d_in[3];
    const float* W2 = (const float*)d_in[4];
    const float* b2 = (const float*)d_in[5];
    float* out = (float*)d_out;

    const int n = in_sizes[0] / 256;   // 50000 (packing requires n < 65536)
    const int E = in_sizes[1] / 2;     // 1.6M
    const int* src = ei;
    const int* dst = ei + E;
    const int nb = (n + 255) / 256;    // bucket count (196)

    // ---- workspace carve-up (256B-aligned) ----
    char* base = (char*)d_ws;
    size_t off = 0;
    auto carve = [&](size_t bytes) -> void* {
        void* p = base + off;
        off = (off + bytes + 255) & ~(size_t)255;
        return p;
    };
    int*   bfill = (int*)  carve(256 * sizeof(int));
    unsigned short* csr = (unsigned short*)carve((size_t)nb * CAP * sizeof(unsigned short));
    int*   rbeg  = (int*)  carve((size_t)n * sizeof(int));
    int*   rend  = (int*)  carve((size_t)n * sizeof(int));
    float* dinv  = (float*)carve((size_t)n * sizeof(float));
    float* hs0   = (float*)carve((size_t)n * 128 * sizeof(float));
    float* hs2   = (float*)carve((size_t)n * 64 * sizeof(float));
    // packed bucket buffer aliases hs0 (nb*CAP*4B = 9.6MB <= 25.6MB);
    // consumed by bucket_build_k before gemm1_k writes hs0 (same stream, sequential)
    unsigned int* bpk = (unsigned int*)hs0;

    hipMemsetAsync(bfill, 0, 256 * sizeof(int), stream);
    bucket_scatter_k<<<(E + CHUNK - 1) / CHUNK, 256, 0, stream>>>(src, dst, bfill, bpk, E);
    bucket_build_k<<<nb, 256, 0, stream>>>(bpk, bfill, csr, rbeg, rend, dinv, n);

    gemm1_k<<<(n + 15) / 16, 128, 0, stream>>>(x, W1, dinv, hs0, n);
    layer1_k<<<(n + 7) / 8, 256, 0, stream>>>(hs0, rbeg, rend, csr, dinv, b1, W2, hs2, n);
    gather2_k<<<(n + 15) / 16, 256, 0, stream>>>(hs2, rbeg, rend, csr, dinv, b2, out, n);
}

// Round 6
// 314.286 us; speedup vs baseline: 2.3658x; 2.3658x over previous
//
#include <hip/hip_runtime.h>
#include <math.h>

#define EPT 16
#define CHUNK (256 * EPT)  // 4096 edges per scatter block
#define CAP 12288          // fixed bucket segment capacity (mean 8192, +45 sigma)

// ================= bucket CSR build (fixed segments, no global scan) =================
// Bucket b = nodes [256b, 256(b+1)); segment [b*CAP, b*CAP + bfill[b]).
// Requires n < 65536 (pack (local<<16)|src).

__global__ void bucket_scatter_k(const int* __restrict__ src, const int* __restrict__ dst,
                                 int* __restrict__ bfill, unsigned int* __restrict__ bpk,
                                 int E) {
    __shared__ int hist[256], gofs[256], lfill[256];
    int t = threadIdx.x;
    int base = blockIdx.x * CHUNK;
    hist[t] = 0;
    lfill[t] = 0;
    __syncthreads();
    int ds[EPT], ss[EPT];
#pragma unroll
    for (int i = 0; i < EPT; ++i) {
        int e = base + i * 256 + t;
        if (e < E) {
            ds[i] = dst[e];
            ss[i] = src[e];
            atomicAdd(&hist[ds[i] >> 8], 1);
        } else {
            ds[i] = -1;
        }
    }
    __syncthreads();
    if (hist[t]) gofs[t] = atomicAdd(&bfill[t], hist[t]);
    __syncthreads();
#pragma unroll
    for (int i = 0; i < EPT; ++i) {
        if (ds[i] >= 0) {
            int b = ds[i] >> 8;
            int p = atomicAdd(&lfill[b], 1);
            int idx = gofs[b] + p;
            if (idx < CAP)  // overflow guard (should never trigger at 45 sigma)
                bpk[b * CAP + idx] = ((unsigned)(ds[i] & 255) << 16) | (unsigned)ss[i];
        }
    }
}

// one block per bucket: local histogram -> deg/dinv/rbeg/rend, LDS counting-sort,
// coalesced csr (ushort) write into the fixed segment
__global__ void bucket_build_k(const unsigned int* __restrict__ bpk,
                               const int* __restrict__ bfill,
                               unsigned short* __restrict__ csr,
                               int* __restrict__ rbeg, int* __restrict__ rend,
                               float* __restrict__ dinv, int n) {
    __shared__ int hist[256], loff[256], lfill[256], tmp[256];
    __shared__ unsigned short scsr[CAP];
    int b = blockIdx.x, t = threadIdx.x;
    int base = b * CAP;
    int bsize = min(bfill[b], CAP);
    hist[t] = 0;
    lfill[t] = 0;
    __syncthreads();
    for (int idx = t; idx < bsize; idx += 256)
        atomicAdd(&hist[bpk[base + idx] >> 16], 1);
    __syncthreads();
    int deg = hist[t];
    tmp[t] = deg;
    __syncthreads();
    for (int off = 1; off < 256; off <<= 1) {
        int a = (t >= off) ? tmp[t - off] : 0;
        __syncthreads();
        tmp[t] += a;
        __syncthreads();
    }
    loff[t] = tmp[t] - deg;  // exclusive
    int node = (b << 8) + t;
    if (node < n) {
        rbeg[node] = base + loff[t];
        rend[node] = base + loff[t] + deg;
        dinv[node] = rsqrtf((float)(deg + 1));  // +1 self-loop
    }
    __syncthreads();
    for (int idx = t; idx < bsize; idx += 256) {
        unsigned u = bpk[base + idx];
        int ln = (int)(u >> 16);
        int sp = atomicAdd(&lfill[ln], 1);
        scsr[loff[ln] + sp] = (unsigned short)(u & 0xFFFFu);
    }
    __syncthreads();
    for (int idx = t; idx < bsize; idx += 256)
        csr[base + idx] = scsr[idx];
}

// ================= GEMM1: hs[n,128] = (x @ W1) * dinv, 16 rows/block =================

__global__ void gemm1_k(const float* __restrict__ x, const float* __restrict__ W,
                        const float* __restrict__ dinv, float* __restrict__ hs, int n) {
    int r0 = blockIdx.x * 16;
    int t = threadIdx.x;  // 0..127 -> output column
    __shared__ float xs[16][256];
    float4* xsv = (float4*)&xs[0][0];
    const float4* xg = (const float4*)(x + (long long)r0 * 256);
    if (r0 + 16 <= n) {
        for (int v = t; v < 16 * 64; v += 128) xsv[v] = xg[v];
    } else {
        for (int v = t; v < 16 * 64; v += 128) {
            int r = v >> 6;
            xsv[v] = (r0 + r < n) ? xg[v] : make_float4(0.f, 0.f, 0.f, 0.f);
        }
    }
    __syncthreads();
    float acc[16];
#pragma unroll
    for (int r = 0; r < 16; ++r) acc[r] = 0.0f;
    for (int k = 0; k < 256; k += 4) {
        float w0 = W[(k + 0) * 128 + t];
        float w1 = W[(k + 1) * 128 + t];
        float w2 = W[(k + 2) * 128 + t];
        float w3 = W[(k + 3) * 128 + t];
#pragma unroll
        for (int r = 0; r < 16; ++r) {
            float4 xv = *(const float4*)&xs[r][k];  // ds_read_b128
            acc[r] += xv.x * w0 + xv.y * w1 + xv.z * w2 + xv.w * w3;
        }
    }
#pragma unroll
    for (int r = 0; r < 16; ++r) {
        int row = r0 + r;
        if (row < n) hs[(long long)row * 128 + t] = acc[r] * dinv[row];
    }
}

// ================= GEMM2: hs2[n,64] = (h1 @ W2) * dinv, 16 rows/block =================

__global__ void gemm2_k(const float* __restrict__ h1, const float* __restrict__ W,
                        const float* __restrict__ dinv, float* __restrict__ hs2, int n) {
    int r0 = blockIdx.x * 16;
    int t = threadIdx.x;  // 0..63 -> output column
    __shared__ float xs[16][128];
    float4* xsv = (float4*)&xs[0][0];
    const float4* xg = (const float4*)(h1 + (long long)r0 * 128);
    if (r0 + 16 <= n) {
        for (int v = t; v < 16 * 32; v += 64) xsv[v] = xg[v];
    } else {
        for (int v = t; v < 16 * 32; v += 64) {
            int r = v >> 5;
            xsv[v] = (r0 + r < n) ? xg[v] : make_float4(0.f, 0.f, 0.f, 0.f);
        }
    }
    __syncthreads();
    float acc[16];
#pragma unroll
    for (int r = 0; r < 16; ++r) acc[r] = 0.0f;
    for (int k = 0; k < 128; k += 4) {
        float w0 = W[(k + 0) * 64 + t];
        float w1 = W[(k + 1) * 64 + t];
        float w2 = W[(k + 2) * 64 + t];
        float w3 = W[(k + 3) * 64 + t];
#pragma unroll
        for (int r = 0; r < 16; ++r) {
            float4 xv = *(const float4*)&xs[r][k];
            acc[r] += xv.x * w0 + xv.y * w1 + xv.z * w2 + xv.w * w3;
        }
    }
#pragma unroll
    for (int r = 0; r < 16; ++r) {
        int row = r0 + r;
        if (row < n) hs2[(long long)row * 64 + t] = acc[r] * dinv[row];
    }
}

// ================= gather-side aggregation (no atomics) =================

// h1[i] = relu(dinv[i]*(hs[i] + sum_nb hs[j]) + b1)   C=128, 32 lanes/node
__global__ void gather1_k(const float* __restrict__ hs, const int* __restrict__ rbeg,
                          const int* __restrict__ rend, const unsigned short* __restrict__ csr,
                          const float* __restrict__ dinv, const float* __restrict__ b1,
                          float* __restrict__ h1, int n) {
    int g = threadIdx.x >> 5;
    int lane = threadIdx.x & 31;
    int i = blockIdx.x * 8 + g;
    if (i >= n) return;
    float4 acc = ((const float4*)(hs + (long long)i * 128))[lane];  // self term
    int beg = rbeg[i], end = rend[i];
    int j = beg;
    for (; j + 8 <= end; j += 8) {
        int s0 = csr[j], s1 = csr[j + 1], s2 = csr[j + 2], s3 = csr[j + 3];
        int s4 = csr[j + 4], s5 = csr[j + 5], s6 = csr[j + 6], s7 = csr[j + 7];
        float4 v0 = ((const float4*)(hs + (long long)s0 * 128))[lane];
        float4 v1 = ((const float4*)(hs + (long long)s1 * 128))[lane];
        float4 v2 = ((const float4*)(hs + (long long)s2 * 128))[lane];
        float4 v3 = ((const float4*)(hs + (long long)s3 * 128))[lane];
        float4 v4 = ((const float4*)(hs + (long long)s4 * 128))[lane];
        float4 v5 = ((const float4*)(hs + (long long)s5 * 128))[lane];
        float4 v6 = ((const float4*)(hs + (long long)s6 * 128))[lane];
        float4 v7 = ((const float4*)(hs + (long long)s7 * 128))[lane];
        acc.x += (v0.x + v1.x + v2.x + v3.x) + (v4.x + v5.x + v6.x + v7.x);
        acc.y += (v0.y + v1.y + v2.y + v3.y) + (v4.y + v5.y + v6.y + v7.y);
        acc.z += (v0.z + v1.z + v2.z + v3.z) + (v4.z + v5.z + v6.z + v7.z);
        acc.w += (v0.w + v1.w + v2.w + v3.w) + (v4.w + v5.w + v6.w + v7.w);
    }
    for (; j < end; ++j) {
        int s0 = csr[j];
        float4 v0 = ((const float4*)(hs + (long long)s0 * 128))[lane];
        acc.x += v0.x; acc.y += v0.y; acc.z += v0.z; acc.w += v0.w;
    }
    float di = dinv[i];
    float4 bb = ((const float4*)b1)[lane];
    float4 o;
    o.x = fmaxf(di * acc.x + bb.x, 0.0f);
    o.y = fmaxf(di * acc.y + bb.y, 0.0f);
    o.z = fmaxf(di * acc.z + bb.z, 0.0f);
    o.w = fmaxf(di * acc.w + bb.w, 0.0f);
    ((float4*)(h1 + (long long)i * 128))[lane] = o;
}

// logits -> pred/prob; C=64, 16 lanes/node. out[0:t)=pred, out[t:2t)=prob
__global__ void gather2_k(const float* __restrict__ hs2, const int* __restrict__ rbeg,
                          const int* __restrict__ rend, const unsigned short* __restrict__ csr,
                          const float* __restrict__ dinv, const float* __restrict__ b2,
                          float* __restrict__ out, int n) {
    int g = threadIdx.x >> 4;
    int lane = threadIdx.x & 15;
    int i = blockIdx.x * 16 + g;
    if (i >= n) return;
    float4 acc = ((const float4*)(hs2 + (long long)i * 64))[lane];  // self term
    int beg = rbeg[i], end = rend[i];
    int j = beg;
    for (; j + 8 <= end; j += 8) {
        int s0 = csr[j], s1 = csr[j + 1], s2 = csr[j + 2], s3 = csr[j + 3];
        int s4 = csr[j + 4], s5 = csr[j + 5], s6 = csr[j + 6], s7 = csr[j + 7];
        float4 v0 = ((const float4*)(hs2 + (long long)s0 * 64))[lane];
        float4 v1 = ((const float4*)(hs2 + (long long)s1 * 64))[lane];
        float4 v2 = ((const float4*)(hs2 + (long long)s2 * 64))[lane];
        float4 v3 = ((const float4*)(hs2 + (long long)s3 * 64))[lane];
        float4 v4 = ((const float4*)(hs2 + (long long)s4 * 64))[lane];
        float4 v5 = ((const float4*)(hs2 + (long long)s5 * 64))[lane];
        float4 v6 = ((const float4*)(hs2 + (long long)s6 * 64))[lane];
        float4 v7 = ((const float4*)(hs2 + (long long)s7 * 64))[lane];
        acc.x += (v0.x + v1.x + v2.x + v3.x) + (v4.x + v5.x + v6.x + v7.x);
        acc.y += (v0.y + v1.y + v2.y + v3.y) + (v4.y + v5.y + v6.y + v7.y);
        acc.z += (v0.z + v1.z + v2.z + v3.z) + (v4.z + v5.z + v6.z + v7.z);
        acc.w += (v0.w + v1.w + v2.w + v3.w) + (v4.w + v5.w + v6.w + v7.w);
    }
    for (; j < end; ++j) {
        int s0 = csr[j];
        float4 v0 = ((const float4*)(hs2 + (long long)s0 * 64))[lane];
        acc.x += v0.x; acc.y += v0.y; acc.z += v0.z; acc.w += v0.w;
    }
    float di = dinv[i];
    float4 bb = ((const float4*)b2)[lane];
    float lx = di * acc.x + bb.x;
    float ly = di * acc.y + bb.y;
    float lz = di * acc.z + bb.z;
    float lw = di * acc.w + bb.w;
    float4 p;
    p.x = 1.0f / (1.0f + expf(-lx));
    p.y = 1.0f / (1.0f + expf(-ly));
    p.z = 1.0f / (1.0f + expf(-lz));
    p.w = 1.0f / (1.0f + expf(-lw));
    long long total = (long long)n * 64;
    long long o0 = (long long)i * 64 + lane * 4;
    float4 pr;
    pr.x = (p.x > 0.5f) ? 1.0f : 0.0f;
    pr.y = (p.y > 0.5f) ? 1.0f : 0.0f;
    pr.z = (p.z > 0.5f) ? 1.0f : 0.0f;
    pr.w = (p.w > 0.5f) ? 1.0f : 0.0f;
    *(float4*)(out + o0) = pr;
    *(float4*)(out + total + o0) = p;
}

// ================= launch =================

extern "C" void kernel_launch(void* const* d_in, const int* in_sizes, int n_in,
                              void* d_out, int out_size, void* d_ws, size_t ws_size,
                              hipStream_t stream) {
    const float* x  = (const float*)d_in[0];
    const int*   ei = (const int*)d_in[1];
    const float* W1 = (const float*)d_in[2];
    const float* b1 = (const float*)d_in[3];
    const float* W2 = (const float*)d_in[4];
    const float* b2 = (const float*)d_in[5];
    float* out = (float*)d_out;

    const int n = in_sizes[0] / 256;   // 50000 (packing requires n < 65536)
    const int E = in_sizes[1] / 2;     // 1.6M
    const int* src = ei;
    const int* dst = ei + E;
    const int nb = (n + 255) / 256;    // bucket count (196)

    // ---- workspace carve-up (256B-aligned) ----
    char* base = (char*)d_ws;
    size_t off = 0;
    auto carve = [&](size_t bytes) -> void* {
        void* p = base + off;
        off = (off + bytes + 255) & ~(size_t)255;
        return p;
    };
    int*   bfill = (int*)  carve(256 * sizeof(int));
    unsigned short* csr = (unsigned short*)carve((size_t)nb * CAP * sizeof(unsigned short));
    int*   rbeg  = (int*)  carve((size_t)n * sizeof(int));
    int*   rend  = (int*)  carve((size_t)n * sizeof(int));
    float* dinv  = (float*)carve((size_t)n * sizeof(float));
    float* hs0   = (float*)carve((size_t)n * 128 * sizeof(float));
    float* h1    = (float*)carve((size_t)n * 128 * sizeof(float));
    float* hs2   = (float*)carve((size_t)n * 64 * sizeof(float));
    // packed bucket buffer aliases hs0 (nb*CAP*4B = 9.6MB <= 25.6MB);
    // consumed by bucket_build_k before gemm1_k writes hs0 (same stream, sequential)
    unsigned int* bpk = (unsigned int*)hs0;

    hipMemsetAsync(bfill, 0, 256 * sizeof(int), stream);
    bucket_scatter_k<<<(E + CHUNK - 1) / CHUNK, 256, 0, stream>>>(src, dst, bfill, bpk, E);
    bucket_build_k<<<nb, 256, 0, stream>>>(bpk, bfill, csr, rbeg, rend, dinv, n);

    gemm1_k<<<(n + 15) / 16, 128, 0, stream>>>(x, W1, dinv, hs0, n);
    gather1_k<<<(n + 7) / 8, 256, 0, stream>>>(hs0, rbeg, rend, csr, dinv, b1, h1, n);
    gemm2_k<<<(n + 15) / 16, 64, 0, stream>>>(h1, W2, dinv, hs2, n);
    gather2_k<<<(n + 15) / 16, 256, 0, stream>>>(hs2, rbeg, rend, csr, dinv, b2, out, n);
}

// Round 7
// 292.443 us; speedup vs baseline: 2.5425x; 1.0747x over previous
//
#include <hip/hip_runtime.h>
#include <math.h>

#define EPT 16
#define CHUNK (256 * EPT)  // 4096 edges per scatter block
#define CAP 12288          // fixed bucket segment capacity (mean 8192, +45 sigma)

// ================= bucket CSR build (fixed segments, no global scan) =================
// Bucket b = nodes [256b, 256(b+1)); segment [b*CAP, b*CAP + bfill[b]).
// Requires n < 65536 (pack (local<<16)|src).

__global__ void bucket_scatter_k(const int* __restrict__ src, const int* __restrict__ dst,
                                 int* __restrict__ bfill, unsigned int* __restrict__ bpk,
                                 int E) {
    __shared__ int hist[256], gofs[256], lfill[256];
    int t = threadIdx.x;
    int base = blockIdx.x * CHUNK;
    hist[t] = 0;
    lfill[t] = 0;
    __syncthreads();
    int ds[EPT], ss[EPT];
#pragma unroll
    for (int i = 0; i < EPT; ++i) {
        int e = base + i * 256 + t;
        if (e < E) {
            ds[i] = dst[e];
            ss[i] = src[e];
            atomicAdd(&hist[ds[i] >> 8], 1);
        } else {
            ds[i] = -1;
        }
    }
    __syncthreads();
    if (hist[t]) gofs[t] = atomicAdd(&bfill[t], hist[t]);
    __syncthreads();
#pragma unroll
    for (int i = 0; i < EPT; ++i) {
        if (ds[i] >= 0) {
            int b = ds[i] >> 8;
            int p = atomicAdd(&lfill[b], 1);
            int idx = gofs[b] + p;
            if (idx < CAP)  // overflow guard (should never trigger at 45 sigma)
                bpk[b * CAP + idx] = ((unsigned)(ds[i] & 255) << 16) | (unsigned)ss[i];
        }
    }
}

// one block per bucket: local histogram -> deg/dinv/rbeg/rend, LDS counting-sort,
// coalesced csr (ushort) write into the fixed segment
__global__ void bucket_build_k(const unsigned int* __restrict__ bpk,
                               const int* __restrict__ bfill,
                               unsigned short* __restrict__ csr,
                               int* __restrict__ rbeg, int* __restrict__ rend,
                               float* __restrict__ dinv, int n) {
    __shared__ int hist[256], loff[256], lfill[256], tmp[256];
    __shared__ unsigned short scsr[CAP];
    int b = blockIdx.x, t = threadIdx.x;
    int base = b * CAP;
    int bsize = min(bfill[b], CAP);
    hist[t] = 0;
    lfill[t] = 0;
    __syncthreads();
    for (int idx = t; idx < bsize; idx += 256)
        atomicAdd(&hist[bpk[base + idx] >> 16], 1);
    __syncthreads();
    int deg = hist[t];
    tmp[t] = deg;
    __syncthreads();
    for (int off = 1; off < 256; off <<= 1) {
        int a = (t >= off) ? tmp[t - off] : 0;
        __syncthreads();
        tmp[t] += a;
        __syncthreads();
    }
    loff[t] = tmp[t] - deg;  // exclusive
    int node = (b << 8) + t;
    if (node < n) {
        rbeg[node] = base + loff[t];
        rend[node] = base + loff[t] + deg;
        dinv[node] = rsqrtf((float)(deg + 1));  // +1 self-loop
    }
    __syncthreads();
    for (int idx = t; idx < bsize; idx += 256) {
        unsigned u = bpk[base + idx];
        int ln = (int)(u >> 16);
        int sp = atomicAdd(&lfill[ln], 1);
        scsr[loff[ln] + sp] = (unsigned short)(u & 0xFFFFu);
    }
    __syncthreads();
    for (int idx = t; idx < bsize; idx += 256)
        csr[base + idx] = scsr[idx];
}

// ================= GEMM1: hs[n,128] = (x @ W1) * dinv, 16 rows/block =================

__global__ void gemm1_k(const float* __restrict__ x, const float* __restrict__ W,
                        const float* __restrict__ dinv, float* __restrict__ hs, int n) {
    int r0 = blockIdx.x * 16;
    int t = threadIdx.x;  // 0..127 -> output column
    __shared__ float xs[16][256];
    float4* xsv = (float4*)&xs[0][0];
    const float4* xg = (const float4*)(x + (long long)r0 * 256);
    if (r0 + 16 <= n) {
        for (int v = t; v < 16 * 64; v += 128) xsv[v] = xg[v];
    } else {
        for (int v = t; v < 16 * 64; v += 128) {
            int r = v >> 6;
            xsv[v] = (r0 + r < n) ? xg[v] : make_float4(0.f, 0.f, 0.f, 0.f);
        }
    }
    __syncthreads();
    float acc[16];
#pragma unroll
    for (int r = 0; r < 16; ++r) acc[r] = 0.0f;
    for (int k = 0; k < 256; k += 4) {
        float w0 = W[(k + 0) * 128 + t];
        float w1 = W[(k + 1) * 128 + t];
        float w2 = W[(k + 2) * 128 + t];
        float w3 = W[(k + 3) * 128 + t];
#pragma unroll
        for (int r = 0; r < 16; ++r) {
            float4 xv = *(const float4*)&xs[r][k];  // ds_read_b128
            acc[r] += xv.x * w0 + xv.y * w1 + xv.z * w2 + xv.w * w3;
        }
    }
#pragma unroll
    for (int r = 0; r < 16; ++r) {
        int row = r0 + r;
        if (row < n) hs[(long long)row * 128 + t] = acc[r] * dinv[row];
    }
}

// ================= GEMM2: hs2[n,64] = (h1 @ W2) * dinv, 16 rows/block =================

__global__ void gemm2_k(const float* __restrict__ h1, const float* __restrict__ W,
                        const float* __restrict__ dinv, float* __restrict__ hs2, int n) {
    int r0 = blockIdx.x * 16;
    int t = threadIdx.x;  // 0..63 -> output column
    __shared__ float xs[16][128];
    float4* xsv = (float4*)&xs[0][0];
    const float4* xg = (const float4*)(h1 + (long long)r0 * 128);
    if (r0 + 16 <= n) {
        for (int v = t; v < 16 * 32; v += 64) xsv[v] = xg[v];
    } else {
        for (int v = t; v < 16 * 32; v += 64) {
            int r = v >> 5;
            xsv[v] = (r0 + r < n) ? xg[v] : make_float4(0.f, 0.f, 0.f, 0.f);
        }
    }
    __syncthreads();
    float acc[16];
#pragma unroll
    for (int r = 0; r < 16; ++r) acc[r] = 0.0f;
    for (int k = 0; k < 128; k += 4) {
        float w0 = W[(k + 0) * 64 + t];
        float w1 = W[(k + 1) * 64 + t];
        float w2 = W[(k + 2) * 64 + t];
        float w3 = W[(k + 3) * 64 + t];
#pragma unroll
        for (int r = 0; r < 16; ++r) {
            float4 xv = *(const float4*)&xs[r][k];
            acc[r] += xv.x * w0 + xv.y * w1 + xv.z * w2 + xv.w * w3;
        }
    }
#pragma unroll
    for (int r = 0; r < 16; ++r) {
        int row = r0 + r;
        if (row < n) hs2[(long long)row * 64 + t] = acc[r] * dinv[row];
    }
}

// ================= channel-split gather passes (no atomics) =================
// Pass gathers only 32 channels [c0, c0+32): 8 lanes/node, 32 nodes/block.
// Working set per pass = n*32*4B = 6.4MB -> better per-XCD L2 hit rate.

// layer1 pass: h1[i, c0:c0+32] = relu(dinv[i]*(hs[i,..] + sum_nb hs[j,..]) + b1[..])
__global__ void gather1p_k(const float* __restrict__ hs, const int* __restrict__ rbeg,
                           const int* __restrict__ rend, const unsigned short* __restrict__ csr,
                           const float* __restrict__ dinv, const float* __restrict__ b1,
                           float* __restrict__ h1, int n, int c0) {
    int g = threadIdx.x >> 3;
    int lane = threadIdx.x & 7;
    int i = blockIdx.x * 32 + g;
    if (i >= n) return;
    const float* hsc = hs + c0;
    float4 acc = ((const float4*)(hsc + (long long)i * 128))[lane];  // self term
    int beg = rbeg[i], end = rend[i];
    int j = beg;
    for (; j + 8 <= end; j += 8) {
        int s0 = csr[j], s1 = csr[j + 1], s2 = csr[j + 2], s3 = csr[j + 3];
        int s4 = csr[j + 4], s5 = csr[j + 5], s6 = csr[j + 6], s7 = csr[j + 7];
        float4 v0 = ((const float4*)(hsc + (long long)s0 * 128))[lane];
        float4 v1 = ((const float4*)(hsc + (long long)s1 * 128))[lane];
        float4 v2 = ((const float4*)(hsc + (long long)s2 * 128))[lane];
        float4 v3 = ((const float4*)(hsc + (long long)s3 * 128))[lane];
        float4 v4 = ((const float4*)(hsc + (long long)s4 * 128))[lane];
        float4 v5 = ((const float4*)(hsc + (long long)s5 * 128))[lane];
        float4 v6 = ((const float4*)(hsc + (long long)s6 * 128))[lane];
        float4 v7 = ((const float4*)(hsc + (long long)s7 * 128))[lane];
        acc.x += (v0.x + v1.x + v2.x + v3.x) + (v4.x + v5.x + v6.x + v7.x);
        acc.y += (v0.y + v1.y + v2.y + v3.y) + (v4.y + v5.y + v6.y + v7.y);
        acc.z += (v0.z + v1.z + v2.z + v3.z) + (v4.z + v5.z + v6.z + v7.z);
        acc.w += (v0.w + v1.w + v2.w + v3.w) + (v4.w + v5.w + v6.w + v7.w);
    }
    for (; j < end; ++j) {
        int s0 = csr[j];
        float4 v0 = ((const float4*)(hsc + (long long)s0 * 128))[lane];
        acc.x += v0.x; acc.y += v0.y; acc.z += v0.z; acc.w += v0.w;
    }
    float di = dinv[i];
    float4 bb = ((const float4*)(b1 + c0))[lane];
    float4 o;
    o.x = fmaxf(di * acc.x + bb.x, 0.0f);
    o.y = fmaxf(di * acc.y + bb.y, 0.0f);
    o.z = fmaxf(di * acc.z + bb.z, 0.0f);
    o.w = fmaxf(di * acc.w + bb.w, 0.0f);
    ((float4*)(h1 + (long long)i * 128 + c0))[lane] = o;
}

// layer2 pass: logits[i, c0:c0+32] -> pred/prob. out[0:t)=pred, out[t:2t)=prob
__global__ void gather2p_k(const float* __restrict__ hs2, const int* __restrict__ rbeg,
                           const int* __restrict__ rend, const unsigned short* __restrict__ csr,
                           const float* __restrict__ dinv, const float* __restrict__ b2,
                           float* __restrict__ out, int n, int c0) {
    int g = threadIdx.x >> 3;
    int lane = threadIdx.x & 7;
    int i = blockIdx.x * 32 + g;
    if (i >= n) return;
    const float* hc = hs2 + c0;
    float4 acc = ((const float4*)(hc + (long long)i * 64))[lane];  // self term
    int beg = rbeg[i], end = rend[i];
    int j = beg;
    for (; j + 8 <= end; j += 8) {
        int s0 = csr[j], s1 = csr[j + 1], s2 = csr[j + 2], s3 = csr[j + 3];
        int s4 = csr[j + 4], s5 = csr[j + 5], s6 = csr[j + 6], s7 = csr[j + 7];
        float4 v0 = ((const float4*)(hc + (long long)s0 * 64))[lane];
        float4 v1 = ((const float4*)(hc + (long long)s1 * 64))[lane];
        float4 v2 = ((const float4*)(hc + (long long)s2 * 64))[lane];
        float4 v3 = ((const float4*)(hc + (long long)s3 * 64))[lane];
        float4 v4 = ((const float4*)(hc + (long long)s4 * 64))[lane];
        float4 v5 = ((const float4*)(hc + (long long)s5 * 64))[lane];
        float4 v6 = ((const float4*)(hc + (long long)s6 * 64))[lane];
        float4 v7 = ((const float4*)(hc + (long long)s7 * 64))[lane];
        acc.x += (v0.x + v1.x + v2.x + v3.x) + (v4.x + v5.x + v6.x + v7.x);
        acc.y += (v0.y + v1.y + v2.y + v3.y) + (v4.y + v5.y + v6.y + v7.y);
        acc.z += (v0.z + v1.z + v2.z + v3.z) + (v4.z + v5.z + v6.z + v7.z);
        acc.w += (v0.w + v1.w + v2.w + v3.w) + (v4.w + v5.w + v6.w + v7.w);
    }
    for (; j < end; ++j) {
        int s0 = csr[j];
        float4 v0 = ((const float4*)(hc + (long long)s0 * 64))[lane];
        acc.x += v0.x; acc.y += v0.y; acc.z += v0.z; acc.w += v0.w;
    }
    float di = dinv[i];
    float4 bb = ((const float4*)(b2 + c0))[lane];
    float lx = di * acc.x + bb.x;
    float ly = di * acc.y + bb.y;
    float lz = di * acc.z + bb.z;
    float lw = di * acc.w + bb.w;
    float4 p;
    p.x = 1.0f / (1.0f + expf(-lx));
    p.y = 1.0f / (1.0f + expf(-ly));
    p.z = 1.0f / (1.0f + expf(-lz));
    p.w = 1.0f / (1.0f + expf(-lw));
    long long total = (long long)n * 64;
    long long o0 = (long long)i * 64 + c0 + lane * 4;
    float4 pr;
    pr.x = (p.x > 0.5f) ? 1.0f : 0.0f;
    pr.y = (p.y > 0.5f) ? 1.0f : 0.0f;
    pr.z = (p.z > 0.5f) ? 1.0f : 0.0f;
    pr.w = (p.w > 0.5f) ? 1.0f : 0.0f;
    *(float4*)(out + o0) = pr;
    *(float4*)(out + total + o0) = p;
}

// ================= launch =================

extern "C" void kernel_launch(void* const* d_in, const int* in_sizes, int n_in,
                              void* d_out, int out_size, void* d_ws, size_t ws_size,
                              hipStream_t stream) {
    const float* x  = (const float*)d_in[0];
    const int*   ei = (const int*)d_in[1];
    const float* W1 = (const float*)d_in[2];
    const float* b1 = (const float*)d_in[3];
    const float* W2 = (const float*)d_in[4];
    const float* b2 = (const float*)d_in[5];
    float* out = (float*)d_out;

    const int n = in_sizes[0] / 256;   // 50000 (packing requires n < 65536)
    const int E = in_sizes[1] / 2;     // 1.6M
    const int* src = ei;
    const int* dst = ei + E;
    const int nb = (n + 255) / 256;    // bucket count (196)

    // ---- workspace carve-up (256B-aligned) ----
    char* base = (char*)d_ws;
    size_t off = 0;
    auto carve = [&](size_t bytes) -> void* {
        void* p = base + off;
        off = (off + bytes + 255) & ~(size_t)255;
        return p;
    };
    int*   bfill = (int*)  carve(256 * sizeof(int));
    unsigned short* csr = (unsigned short*)carve((size_t)nb * CAP * sizeof(unsigned short));
    int*   rbeg  = (int*)  carve((size_t)n * sizeof(int));
    int*   rend  = (int*)  carve((size_t)n * sizeof(int));
    float* dinv  = (float*)carve((size_t)n * sizeof(float));
    float* hs0   = (float*)carve((size_t)n * 128 * sizeof(float));
    float* h1    = (float*)carve((size_t)n * 128 * sizeof(float));
    float* hs2   = (float*)carve((size_t)n * 64 * sizeof(float));
    // packed bucket buffer aliases hs0 (nb*CAP*4B = 9.6MB <= 25.6MB);
    // consumed by bucket_build_k before gemm1_k writes hs0 (same stream, sequential)
    unsigned int* bpk = (unsigned int*)hs0;

    hipMemsetAsync(bfill, 0, 256 * sizeof(int), stream);
    bucket_scatter_k<<<(E + CHUNK - 1) / CHUNK, 256, 0, stream>>>(src, dst, bfill, bpk, E);
    bucket_build_k<<<nb, 256, 0, stream>>>(bpk, bfill, csr, rbeg, rend, dinv, n);

    gemm1_k<<<(n + 15) / 16, 128, 0, stream>>>(x, W1, dinv, hs0, n);

    const int gblk = (n + 31) / 32;
    for (int c0 = 0; c0 < 128; c0 += 32)
        gather1p_k<<<gblk, 256, 0, stream>>>(hs0, rbeg, rend, csr, dinv, b1, h1, n, c0);

    gemm2_k<<<(n + 15) / 16, 64, 0, stream>>>(h1, W2, dinv, hs2, n);

    for (int c0 = 0; c0 < 64; c0 += 32)
        gather2p_k<<<gblk, 256, 0, stream>>>(hs2, rbeg, rend, csr, dinv, b2, out, n, c0);
}

// Round 8
// 288.890 us; speedup vs baseline: 2.5737x; 1.0123x over previous
//
#include <hip/hip_runtime.h>
#include <math.h>

#define EPT 16
#define CHUNK (256 * EPT)  // 4096 edges per scatter block
#define CAP 12288          // fixed bucket segment capacity (mean 8192, +45 sigma)

// ================= bucket CSR build (fixed segments, no global scan) =================
// Bucket b = nodes [256b, 256(b+1)); segment [b*CAP, b*CAP + bfill[b]).
// Requires n < 65536 (pack (local<<16)|src).

__global__ void bucket_scatter_k(const int* __restrict__ src, const int* __restrict__ dst,
                                 int* __restrict__ bfill, unsigned int* __restrict__ bpk,
                                 int E) {
    __shared__ int hist[256], gofs[256], lfill[256];
    int t = threadIdx.x;
    int base = blockIdx.x * CHUNK;
    hist[t] = 0;
    lfill[t] = 0;
    __syncthreads();
    int ds[EPT], ss[EPT];
#pragma unroll
    for (int i = 0; i < EPT; ++i) {
        int e = base + i * 256 + t;
        if (e < E) {
            ds[i] = dst[e];
            ss[i] = src[e];
            atomicAdd(&hist[ds[i] >> 8], 1);
        } else {
            ds[i] = -1;
        }
    }
    __syncthreads();
    if (hist[t]) gofs[t] = atomicAdd(&bfill[t], hist[t]);
    __syncthreads();
#pragma unroll
    for (int i = 0; i < EPT; ++i) {
        if (ds[i] >= 0) {
            int b = ds[i] >> 8;
            int p = atomicAdd(&lfill[b], 1);
            int idx = gofs[b] + p;
            if (idx < CAP)  // overflow guard (should never trigger at 45 sigma)
                bpk[b * CAP + idx] = ((unsigned)(ds[i] & 255) << 16) | (unsigned)ss[i];
        }
    }
}

// one block per bucket: local histogram -> deg/dinv/rbeg/rend, LDS counting-sort,
// coalesced csr (ushort) write into the fixed segment
__global__ void bucket_build_k(const unsigned int* __restrict__ bpk,
                               const int* __restrict__ bfill,
                               unsigned short* __restrict__ csr,
                               int* __restrict__ rbeg, int* __restrict__ rend,
                               float* __restrict__ dinv, int n) {
    __shared__ int hist[256], loff[256], lfill[256], tmp[256];
    __shared__ unsigned short scsr[CAP];
    int b = blockIdx.x, t = threadIdx.x;
    int base = b * CAP;
    int bsize = min(bfill[b], CAP);
    hist[t] = 0;
    lfill[t] = 0;
    __syncthreads();
    for (int idx = t; idx < bsize; idx += 256)
        atomicAdd(&hist[bpk[base + idx] >> 16], 1);
    __syncthreads();
    int deg = hist[t];
    tmp[t] = deg;
    __syncthreads();
    for (int off = 1; off < 256; off <<= 1) {
        int a = (t >= off) ? tmp[t - off] : 0;
        __syncthreads();
        tmp[t] += a;
        __syncthreads();
    }
    loff[t] = tmp[t] - deg;  // exclusive
    int node = (b << 8) + t;
    if (node < n) {
        rbeg[node] = base + loff[t];
        rend[node] = base + loff[t] + deg;
        dinv[node] = rsqrtf((float)(deg + 1));  // +1 self-loop
    }
    __syncthreads();
    for (int idx = t; idx < bsize; idx += 256) {
        unsigned u = bpk[base + idx];
        int ln = (int)(u >> 16);
        int sp = atomicAdd(&lfill[ln], 1);
        scsr[loff[ln] + sp] = (unsigned short)(u & 0xFFFFu);
    }
    __syncthreads();
    for (int idx = t; idx < bsize; idx += 256)
        csr[base + idx] = scsr[idx];
}

// ================= GEMM1: hs[n,128] = (x @ W1) * dinv =================
// 64 rows x 128 cols per block, 256 threads, thread tile = 8 rows x 4 cols.
// k staged in 64-wide LDS chunks; each ds_read_b128 feeds 16 FMAs.

__global__ __launch_bounds__(256) void gemm1_k(const float* __restrict__ x,
                                               const float* __restrict__ W,
                                               const float* __restrict__ dinv,
                                               float* __restrict__ hs, int n) {
    __shared__ float xs[64][64];  // 16 KB
    int tid = threadIdx.x;
    int cg = tid & 31;   // cols cg*4 .. +3
    int rg = tid >> 5;   // rows rg*8 .. +7
    int r0 = blockIdx.x * 64;
    float acc[8][4];
#pragma unroll
    for (int r = 0; r < 8; ++r)
#pragma unroll
        for (int c = 0; c < 4; ++c) acc[r][c] = 0.0f;

    for (int kc = 0; kc < 4; ++kc) {  // 4 chunks of 64 k
        __syncthreads();
        for (int v = tid; v < 64 * 16; v += 256) {
            int r = v >> 4;
            int k4 = v & 15;
            float4 val = make_float4(0.f, 0.f, 0.f, 0.f);
            int row = r0 + r;
            if (row < n) val = *(const float4*)(x + (long long)row * 256 + kc * 64 + k4 * 4);
            *(float4*)&xs[r][k4 * 4] = val;
        }
        __syncthreads();
        const float* Wp = W + (long long)(kc * 64) * 128 + cg * 4;
#pragma unroll 4
        for (int k4 = 0; k4 < 16; ++k4) {
            float4 w0 = *(const float4*)(Wp + (k4 * 4 + 0) * 128);
            float4 w1 = *(const float4*)(Wp + (k4 * 4 + 1) * 128);
            float4 w2 = *(const float4*)(Wp + (k4 * 4 + 2) * 128);
            float4 w3 = *(const float4*)(Wp + (k4 * 4 + 3) * 128);
#pragma unroll
            for (int r = 0; r < 8; ++r) {
                float4 xv = *(const float4*)&xs[rg * 8 + r][k4 * 4];  // broadcast read
                acc[r][0] += xv.x * w0.x + xv.y * w1.x + xv.z * w2.x + xv.w * w3.x;
                acc[r][1] += xv.x * w0.y + xv.y * w1.y + xv.z * w2.y + xv.w * w3.y;
                acc[r][2] += xv.x * w0.z + xv.y * w1.z + xv.z * w2.z + xv.w * w3.z;
                acc[r][3] += xv.x * w0.w + xv.y * w1.w + xv.z * w2.w + xv.w * w3.w;
            }
        }
    }
#pragma unroll
    for (int r = 0; r < 8; ++r) {
        int row = r0 + rg * 8 + r;
        if (row < n) {
            float di = dinv[row];
            float4 o = make_float4(acc[r][0] * di, acc[r][1] * di,
                                   acc[r][2] * di, acc[r][3] * di);
            *(float4*)(hs + (long long)row * 128 + cg * 4) = o;
        }
    }
}

// ================= GEMM2: hs2[n,64] = (h1 @ W2) * dinv =================
// 128 rows x 64 cols per block, 256 threads, thread tile = 8 rows x 4 cols.

__global__ __launch_bounds__(256) void gemm2_k(const float* __restrict__ h1,
                                               const float* __restrict__ W,
                                               const float* __restrict__ dinv,
                                               float* __restrict__ hs2, int n) {
    __shared__ float xs[128][64];  // 32 KB
    int tid = threadIdx.x;
    int cg = tid & 15;   // cols cg*4 .. +3
    int rg = tid >> 4;   // rows rg*8 .. +7
    int r0 = blockIdx.x * 128;
    float acc[8][4];
#pragma unroll
    for (int r = 0; r < 8; ++r)
#pragma unroll
        for (int c = 0; c < 4; ++c) acc[r][c] = 0.0f;

    for (int kc = 0; kc < 2; ++kc) {  // 2 chunks of 64 k
        __syncthreads();
        for (int v = tid; v < 128 * 16; v += 256) {
            int r = v >> 4;
            int k4 = v & 15;
            float4 val = make_float4(0.f, 0.f, 0.f, 0.f);
            int row = r0 + r;
            if (row < n) val = *(const float4*)(h1 + (long long)row * 128 + kc * 64 + k4 * 4);
            *(float4*)&xs[r][k4 * 4] = val;
        }
        __syncthreads();
        const float* Wp = W + (long long)(kc * 64) * 64 + cg * 4;
#pragma unroll 4
        for (int k4 = 0; k4 < 16; ++k4) {
            float4 w0 = *(const float4*)(Wp + (k4 * 4 + 0) * 64);
            float4 w1 = *(const float4*)(Wp + (k4 * 4 + 1) * 64);
            float4 w2 = *(const float4*)(Wp + (k4 * 4 + 2) * 64);
            float4 w3 = *(const float4*)(Wp + (k4 * 4 + 3) * 64);
#pragma unroll
            for (int r = 0; r < 8; ++r) {
                float4 xv = *(const float4*)&xs[rg * 8 + r][k4 * 4];
                acc[r][0] += xv.x * w0.x + xv.y * w1.x + xv.z * w2.x + xv.w * w3.x;
                acc[r][1] += xv.x * w0.y + xv.y * w1.y + xv.z * w2.y + xv.w * w3.y;
                acc[r][2] += xv.x * w0.z + xv.y * w1.z + xv.z * w2.z + xv.w * w3.z;
                acc[r][3] += xv.x * w0.w + xv.y * w1.w + xv.z * w2.w + xv.w * w3.w;
            }
        }
    }
#pragma unroll
    for (int r = 0; r < 8; ++r) {
        int row = r0 + rg * 8 + r;
        if (row < n) {
            float di = dinv[row];
            float4 o = make_float4(acc[r][0] * di, acc[r][1] * di,
                                   acc[r][2] * di, acc[r][3] * di);
            *(float4*)(hs2 + (long long)row * 64 + cg * 4) = o;
        }
    }
}

// ================= channel-split gather passes (no atomics) =================
// Pass gathers only 32 channels [c0, c0+32): 8 lanes/node, 32 nodes/block.
// Working set per pass = n*32*4B = 6.4MB -> better per-XCD L2 hit rate.

// layer1 pass: h1[i, c0:c0+32] = relu(dinv[i]*(hs[i,..] + sum_nb hs[j,..]) + b1[..])
__global__ void gather1p_k(const float* __restrict__ hs, const int* __restrict__ rbeg,
                           const int* __restrict__ rend, const unsigned short* __restrict__ csr,
                           const float* __restrict__ dinv, const float* __restrict__ b1,
                           float* __restrict__ h1, int n, int c0) {
    int g = threadIdx.x >> 3;
    int lane = threadIdx.x & 7;
    int i = blockIdx.x * 32 + g;
    if (i >= n) return;
    const float* hsc = hs + c0;
    float4 acc = ((const float4*)(hsc + (long long)i * 128))[lane];  // self term
    int beg = rbeg[i], end = rend[i];
    int j = beg;
    for (; j + 8 <= end; j += 8) {
        int s0 = csr[j], s1 = csr[j + 1], s2 = csr[j + 2], s3 = csr[j + 3];
        int s4 = csr[j + 4], s5 = csr[j + 5], s6 = csr[j + 6], s7 = csr[j + 7];
        float4 v0 = ((const float4*)(hsc + (long long)s0 * 128))[lane];
        float4 v1 = ((const float4*)(hsc + (long long)s1 * 128))[lane];
        float4 v2 = ((const float4*)(hsc + (long long)s2 * 128))[lane];
        float4 v3 = ((const float4*)(hsc + (long long)s3 * 128))[lane];
        float4 v4 = ((const float4*)(hsc + (long long)s4 * 128))[lane];
        float4 v5 = ((const float4*)(hsc + (long long)s5 * 128))[lane];
        float4 v6 = ((const float4*)(hsc + (long long)s6 * 128))[lane];
        float4 v7 = ((const float4*)(hsc + (long long)s7 * 128))[lane];
        acc.x += (v0.x + v1.x + v2.x + v3.x) + (v4.x + v5.x + v6.x + v7.x);
        acc.y += (v0.y + v1.y + v2.y + v3.y) + (v4.y + v5.y + v6.y + v7.y);
        acc.z += (v0.z + v1.z + v2.z + v3.z) + (v4.z + v5.z + v6.z + v7.z);
        acc.w += (v0.w + v1.w + v2.w + v3.w) + (v4.w + v5.w + v6.w + v7.w);
    }
    for (; j < end; ++j) {
        int s0 = csr[j];
        float4 v0 = ((const float4*)(hsc + (long long)s0 * 128))[lane];
        acc.x += v0.x; acc.y += v0.y; acc.z += v0.z; acc.w += v0.w;
    }
    float di = dinv[i];
    float4 bb = ((const float4*)(b1 + c0))[lane];
    float4 o;
    o.x = fmaxf(di * acc.x + bb.x, 0.0f);
    o.y = fmaxf(di * acc.y + bb.y, 0.0f);
    o.z = fmaxf(di * acc.z + bb.z, 0.0f);
    o.w = fmaxf(di * acc.w + bb.w, 0.0f);
    ((float4*)(h1 + (long long)i * 128 + c0))[lane] = o;
}

// layer2 pass: logits[i, c0:c0+32] -> pred/prob. out[0:t)=pred, out[t:2t)=prob
__global__ void gather2p_k(const float* __restrict__ hs2, const int* __restrict__ rbeg,
                           const int* __restrict__ rend, const unsigned short* __restrict__ csr,
                           const float* __restrict__ dinv, const float* __restrict__ b2,
                           float* __restrict__ out, int n, int c0) {
    int g = threadIdx.x >> 3;
    int lane = threadIdx.x & 7;
    int i = blockIdx.x * 32 + g;
    if (i >= n) return;
    const float* hc = hs2 + c0;
    float4 acc = ((const float4*)(hc + (long long)i * 64))[lane];  // self term
    int beg = rbeg[i], end = rend[i];
    int j = beg;
    for (; j + 8 <= end; j += 8) {
        int s0 = csr[j], s1 = csr[j + 1], s2 = csr[j + 2], s3 = csr[j + 3];
        int s4 = csr[j + 4], s5 = csr[j + 5], s6 = csr[j + 6], s7 = csr[j + 7];
        float4 v0 = ((const float4*)(hc + (long long)s0 * 64))[lane];
        float4 v1 = ((const float4*)(hc + (long long)s1 * 64))[lane];
        float4 v2 = ((const float4*)(hc + (long long)s2 * 64))[lane];
        float4 v3 = ((const float4*)(hc + (long long)s3 * 64))[lane];
        float4 v4 = ((const float4*)(hc + (long long)s4 * 64))[lane];
        float4 v5 = ((const float4*)(hc + (long long)s5 * 64))[lane];
        float4 v6 = ((const float4*)(hc + (long long)s6 * 64))[lane];
        float4 v7 = ((const float4*)(hc + (long long)s7 * 64))[lane];
        acc.x += (v0.x + v1.x + v2.x + v3.x) + (v4.x + v5.x + v6.x + v7.x);
        acc.y += (v0.y + v1.y + v2.y + v3.y) + (v4.y + v5.y + v6.y + v7.y);
        acc.z += (v0.z + v1.z + v2.z + v3.z) + (v4.z + v5.z + v6.z + v7.z);
        acc.w += (v0.w + v1.w + v2.w + v3.w) + (v4.w + v5.w + v6.w + v7.w);
    }
    for (; j < end; ++j) {
        int s0 = csr[j];
        float4 v0 = ((const float4*)(hc + (long long)s0 * 64))[lane];
        acc.x += v0.x; acc.y += v0.y; acc.z += v0.z; acc.w += v0.w;
    }
    float di = dinv[i];
    float4 bb = ((const float4*)(b2 + c0))[lane];
    float lx = di * acc.x + bb.x;
    float ly = di * acc.y + bb.y;
    float lz = di * acc.z + bb.z;
    float lw = di * acc.w + bb.w;
    float4 p;
    p.x = 1.0f / (1.0f + expf(-lx));
    p.y = 1.0f / (1.0f + expf(-ly));
    p.z = 1.0f / (1.0f + expf(-lz));
    p.w = 1.0f / (1.0f + expf(-lw));
    long long total = (long long)n * 64;
    long long o0 = (long long)i * 64 + c0 + lane * 4;
    float4 pr;
    pr.x = (p.x > 0.5f) ? 1.0f : 0.0f;
    pr.y = (p.y > 0.5f) ? 1.0f : 0.0f;
    pr.z = (p.z > 0.5f) ? 1.0f : 0.0f;
    pr.w = (p.w > 0.5f) ? 1.0f : 0.0f;
    *(float4*)(out + o0) = pr;
    *(float4*)(out + total + o0) = p;
}

// ================= launch =================

extern "C" void kernel_launch(void* const* d_in, const int* in_sizes, int n_in,
                              void* d_out, int out_size, void* d_ws, size_t ws_size,
                              hipStream_t stream) {
    const float* x  = (const float*)d_in[0];
    const int*   ei = (const int*)d_in[1];
    const float* W1 = (const float*)d_in[2];
    const float* b1 = (const float*)d_in[3];
    const float* W2 = (const float*)d_in[4];
    const float* b2 = (const float*)d_in[5];
    float* out = (float*)d_out;

    const int n = in_sizes[0] / 256;   // 50000 (packing requires n < 65536)
    const int E = in_sizes[1] / 2;     // 1.6M
    const int* src = ei;
    const int* dst = ei + E;
    const int nb = (n + 255) / 256;    // bucket count (196)

    // ---- workspace carve-up (256B-aligned) ----
    char* base = (char*)d_ws;
    size_t off = 0;
    auto carve = [&](size_t bytes) -> void* {
        void* p = base + off;
        off = (off + bytes + 255) & ~(size_t)255;
        return p;
    };
    int*   bfill = (int*)  carve(256 * sizeof(int));
    unsigned short* csr = (unsigned short*)carve((size_t)nb * CAP * sizeof(unsigned short));
    int*   rbeg  = (int*)  carve((size_t)n * sizeof(int));
    int*   rend  = (int*)  carve((size_t)n * sizeof(int));
    float* dinv  = (float*)carve((size_t)n * sizeof(float));
    float* hs0   = (float*)carve((size_t)n * 128 * sizeof(float));
    float* h1    = (float*)carve((size_t)n * 128 * sizeof(float));
    float* hs2   = (float*)carve((size_t)n * 64 * sizeof(float));
    // packed bucket buffer aliases hs0 (nb*CAP*4B = 9.6MB <= 25.6MB);
    // consumed by bucket_build_k before gemm1_k writes hs0 (same stream, sequential)
    unsigned int* bpk = (unsigned int*)hs0;

    hipMemsetAsync(bfill, 0, 256 * sizeof(int), stream);
    bucket_scatter_k<<<(E + CHUNK - 1) / CHUNK, 256, 0, stream>>>(src, dst, bfill, bpk, E);
    bucket_build_k<<<nb, 256, 0, stream>>>(bpk, bfill, csr, rbeg, rend, dinv, n);

    gemm1_k<<<(n + 63) / 64, 256, 0, stream>>>(x, W1, dinv, hs0, n);

    const int gblk = (n + 31) / 32;
    for (int c0 = 0; c0 < 128; c0 += 32)
        gather1p_k<<<gblk, 256, 0, stream>>>(hs0, rbeg, rend, csr, dinv, b1, h1, n, c0);

    gemm2_k<<<(n + 127) / 128, 256, 0, stream>>>(h1, W2, dinv, hs2, n);

    for (int c0 = 0; c0 < 64; c0 += 32)
        gather2p_k<<<gblk, 256, 0, stream>>>(hs2, rbeg, rend, csr, dinv, b2, out, n, c0);
}